// Round 6
// baseline (3477.887 us; speedup 1.0000x reference)
//
#include <hip/hip_runtime.h>
#include <math.h>
#include <stdint.h>

#define BATCH 131072
#define KDIM  256
#define ODIM  1024

#define BM 128
#define BN 128
#define BK 32
#define NTILE (KDIM / BK)    // 8 k-tiles
#define NROWT (BATCH / BM)   // 1024 row tiles
#define NCOLT (ODIM / BN)    // 8 col tiles
#define NXCD  8

// Native clang vector: supports [] with constant index; required by
// __builtin_nontemporal_store (round-3 lesson).
typedef float vf4 __attribute__((ext_vector_type(4)));
typedef const __attribute__((address_space(1))) uint32_t* gas1_t;
typedef __attribute__((address_space(3)))       uint32_t* las3_t;

// ---------------------------------------------------------------------------
// Tiled fp32 GEMM + fused activations.
//
// NUMERICS CONTRACT: reference is numpy fp32 sgemm — per output element one
// fp32 accumulator, fused FMAs, k strictly ascending 0..255. No MFMA, no
// k-splitting, no reassociation. tan in fp64 of the fp32 argument near poles.
// This round changes only WHERE tiles live in LDS and WHO stages them; per-
// element summation order unchanged -> absmax must stay exactly 0.015625.
//
// Round-5 post-mortem: XCD swizzle fixed FETCH (526->70MB) but dur only -3%:
// staging cost is issue-side, not latency-side. 32 scalar ds_write_b32/thread
// /tile (the [k][row] transpose) with a 4-way bank conflict (5.03e7 cycles
// ~9% of runtime) + address VALU dominated the inter-barrier phase.
//
// This round: direct-to-LDS staging, zero ds_writes.
//   * LDS layout [row][k], 128B/row, NO pad (global_load_lds writes linearly:
//     lane l -> dst + l*16B = row (l>>3), slot (l&7) -- exactly our layout).
//   * Bank-conflict fix is an XOR chunk swizzle applied BOTH sides (m231
//     rule): 16B slot s of row r holds global k-chunk s ^ ((r>>2)&7).
//     - staging: global src addr pre-swizzled per lane (coalescing kept:
//       XOR permutes within each 128B segment)
//     - reads: fragment for k-group g read at slot g ^ key (key uniform per
//       thread; XOR with literal g folds to 1 VALU op per group)
//   * Read conflicts after swizzle: A = 16-lane broadcast, 4 bank-quads
//     (free); B = 16 addrs over 8 quads = 2-way (free).
//   * Inner loop consumes k in groups of 4 (float4-along-k); per element
//     k = 4g+kk still strictly ascending.
// ---------------------------------------------------------------------------
__global__ __launch_bounds__(256) void gemm_act(
    const float* __restrict__ x,      // [BATCH, KDIM]
    const float* __restrict__ w,      // [ODIM, KDIM]
    float* __restrict__ out)          // [BATCH, ODIM]
{
    __shared__ float As[BM * BK];     // row r at float offset r*BK
    __shared__ float Bs[BN * BK];

    // XCD-chunked bijective swizzle (round 5: keeps x in own-XCD L2).
    const int bid     = blockIdx.x;
    const int xcd     = bid & (NXCD - 1);
    const int jb      = bid >> 3;
    const int rowtile = xcd * (NROWT / NXCD) + (jb >> 3);
    const int coltile = jb & (NCOLT - 1);
    const int row0    = rowtile * BM;
    const int col0    = coltile * BN;

    const int tid  = threadIdx.x;
    const int wave = tid >> 6;
    const int lane = tid & 63;
    const int lr   = lane >> 3;   // row within an 8-row staging group
    const int ls   = lane & 7;    // 16B slot within the row

    // Per-lane global source pointers: linear LDS dest + inverse-swizzled src.
    // Staging inst m covers rows wave*32 + m*8 .. +7 of the tile.
    const float* srcA[4];
    const float* srcB[4];
    #pragma unroll
    for (int m = 0; m < 4; ++m) {
        const int r = wave * 32 + m * 8 + lr;
        const int c = (ls ^ ((r >> 2) & 7)) << 2;   // swizzled k offset (floats)
        srcA[m] = x + (size_t)(row0 + r) * KDIM + c;
        srcB[m] = w + (size_t)(col0 + r) * KDIM + c;
    }

    const int ty = (tid >> 4) << 2;   // row frag base (lower half-tile)
    const int tx = (tid & 15) << 2;   // col frag base (lower half-tile)
    const int tA = (tid >> 4) & 7;    // A chunk-swizzle key (same for +64 rows)
    const int tB = tid & 7;           // B chunk-swizzle key (same for +64 cols)

    // acc[i][jh*4+j]: rows {ty+i, 64+ty+i}, cols {tx+j, 64+tx+j}
    float acc[8][8] = {};

    #pragma unroll
    for (int t = 0; t < NTILE; ++t) {
        __syncthreads();   // previous tile's LDS readers are done

        // Stage both tiles direct to LDS: 8 instructions, no reg round-trip,
        // no ds_write, no write bank conflicts.
        #pragma unroll
        for (int m = 0; m < 4; ++m) {
            __builtin_amdgcn_global_load_lds(
                (gas1_t)(const void*)(srcA[m] + t * BK),
                (las3_t)(void*)&As[(wave * 32 + m * 8) * BK], 16, 0, 0);
            __builtin_amdgcn_global_load_lds(
                (gas1_t)(const void*)(srcB[m] + t * BK),
                (las3_t)(void*)&Bs[(wave * 32 + m * 8) * BK], 16, 0, 0);
        }
        __syncthreads();   // compiler drains vmcnt(0) before this barrier

        // k-groups of 4; per element k = 4g+kk strictly ascending.
        #pragma unroll
        for (int g = 0; g < 8; ++g) {
            const int cA = (g ^ tA) << 2;   // swizzled 16B-slot, float offset
            const int cB = (g ^ tB) << 2;

            vf4 A[8];
            #pragma unroll
            for (int i = 0; i < 4; ++i) {
                A[i]     = *(const vf4*)&As[(ty + i) * BK + cA];
                A[4 + i] = *(const vf4*)&As[(64 + ty + i) * BK + cA];
            }
            #pragma unroll
            for (int jh = 0; jh < 2; ++jh) {
                vf4 B[4];
                #pragma unroll
                for (int j = 0; j < 4; ++j)
                    B[j] = *(const vf4*)&Bs[(jh * 64 + tx + j) * BK + cB];
                #pragma unroll
                for (int kk = 0; kk < 4; ++kk)
                    #pragma unroll
                    for (int i = 0; i < 8; ++i)
                        #pragma unroll
                        for (int j = 0; j < 4; ++j)
                            acc[i][jh * 4 + j] =
                                fmaf(A[i][kk], B[j][kk], acc[i][jh * 4 + j]);
            }
        }
    }

    // Epilogue: cols (tx or 64+tx) + {0,1,2,3} => residues {0,1,2,3}
    //           = {linear, cos, sin, tan}. Non-temporal stores (never re-read).
    #pragma unroll
    for (int i = 0; i < 8; ++i) {
        const int row = row0 + (i < 4 ? ty + i : 64 + ty + (i - 4));
        #pragma unroll
        for (int jh = 0; jh < 2; ++jh) {
            const int colb = col0 + jh * 64 + tx;
            const float y0 = acc[i][jh * 4 + 0];
            const float y1 = acc[i][jh * 4 + 1];
            const float y2 = acc[i][jh * 4 + 2];
            const float y3 = acc[i][jh * 4 + 3];

            vf4 o;
            o.x = y0;
            o.y = __cosf(y1);
            o.z = __sinf(y2);
            o.w = tanf(y3);

            // Near a pole, evaluate tan of the SAME fp32 argument in fp64 so
            // the only deviation from numpy's tan is final rounding (<=1-2 ulp).
            const float m_   = rintf(y3 * 0.31830988618379067f);     // round(y/pi)
            const float r2   = fmaf(-m_, 3.14159265358979323f, y3);  // y - m*pi
            const float dist = fabsf(fabsf(r2) - 1.57079632679489662f);
            if (dist < 1e-2f) {
                o.w = (float)tan((double)y3);
            }

            __builtin_nontemporal_store(o, (vf4*)(out + (size_t)row * ODIM + colb));
        }
    }
}

// ---------------------------------------------------------------------------
extern "C" void kernel_launch(void* const* d_in, const int* in_sizes, int n_in,
                              void* d_out, int out_size, void* d_ws, size_t ws_size,
                              hipStream_t stream)
{
    const float* x = (const float*)d_in[0];
    const float* w = (const float*)d_in[1];
    float* out = (float*)d_out;

    dim3 grid(NROWT * NCOLT);   // 8192 blocks, 1D, swizzled in-kernel
    gemm_act<<<grid, 256, 0, stream>>>(x, w, out);
}